// Round 10
// baseline (320.109 us; speedup 1.0000x reference)
//
#include <hip/hip_runtime.h>
#include <cstdint>

// Multihead self-attention, B=2 S=2048 E=1024 H=16 D=64.
// fp32 in/out; internal bf16 MFMA, fp32 accum.
// R10: attn — K fragments prefetched tile-ahead straight into VGPRs (no sK),
// V double-buffered tile-ahead via async16 -> ONE syncthreads per KV tile.
// LDS 40KB. prep kernel fuses x-convert + both weight transposes (6->4 launches).

typedef __bf16 bf16;
typedef __bf16 bf16x4 __attribute__((ext_vector_type(4)));
typedef __bf16 bf16x8 __attribute__((ext_vector_type(8)));
typedef float floatx4 __attribute__((ext_vector_type(4)));
typedef uint32_t u32;

#define B_ 2
#define S_ 2048
#define E_ 1024
#define H_ 16
#define D_ 64

__device__ __forceinline__ void async16(const void* g, const void* l) {
  __builtin_amdgcn_global_load_lds(
      (u32 __attribute__((address_space(1)))*)g,
      (u32 __attribute__((address_space(3)))*)l,
      16, 0, 0);
}

// ---------------------------------------------------------------------------
// prep: blockIdx.x < 3072  -> transpose+cvt wqkv (1024x3072 -> 3072x1024 bf16)
//       3072..4095         -> transpose+cvt wout (1024x1024)
//       4096..8191         -> x fp32 -> bf16 elementwise
// ---------------------------------------------------------------------------
__device__ __forceinline__ void trans_tile(
    bf16* __restrict__ dst, const float* __restrict__ src, int R, int C,
    int c0, int r0, float (*t)[33]) {
  const int tx = threadIdx.x & 31, ty = threadIdx.x >> 5;
#pragma unroll
  for (int j = 0; j < 4; ++j)
    t[ty + 8 * j][tx] = src[(size_t)(r0 + ty + 8 * j) * C + c0 + tx];
  __syncthreads();
#pragma unroll
  for (int j = 0; j < 4; ++j)
    dst[(size_t)(c0 + ty + 8 * j) * R + r0 + tx] = (bf16)t[tx][ty + 8 * j];
}

__global__ __launch_bounds__(256) void prep(
    bf16* __restrict__ xb, bf16* __restrict__ wqkvT, bf16* __restrict__ woutT,
    const float* __restrict__ x, const float* __restrict__ wqkv,
    const float* __restrict__ wout) {
  __shared__ float t[32][33];
  const int id = blockIdx.x;
  if (id < 3072) {
    trans_tile(wqkvT, wqkv, 1024, 3072, (id % 96) * 32, (id / 96) * 32, t);
  } else if (id < 4096) {
    const int i2 = id - 3072;
    trans_tile(woutT, wout, 1024, 1024, (i2 % 32) * 32, (i2 / 32) * 32, t);
  } else {
    const int i = (id - 4096) * 256 + threadIdx.x;  // floatx4 index, exact fit
    floatx4 v = ((const floatx4*)x)[i];
    bf16x4 o;
#pragma unroll
    for (int e = 0; e < 4; ++e) o[e] = (bf16)v[e];
    ((bf16x4*)xb)[i] = o;
  }
}

// ---------------------------------------------------------------------------
// QKV GEMM, 128x128 tile (m97 structure). M=4096, N=3072, K=1024.
// n0<2048 (Q,K) -> qkv rows; n0>=2048 (V) -> vt transposed (repack fused).
// ---------------------------------------------------------------------------
__global__ __launch_bounds__(256) void gemm_qkv(
    bf16* __restrict__ qkv, bf16* __restrict__ vt,
    const bf16* __restrict__ A, const bf16* __restrict__ Bt) {
  const int N_ = 3072, K_ = 1024;
  __shared__ alignas(16) bf16 sA[8192];
  __shared__ alignas(16) bf16 sB[8192];
  const int tid = threadIdx.x;
  const int lane = tid & 63;
  const int w = tid >> 6;
  const int wr = (w >> 1) * 64, wc = (w & 1) * 64;
  const int l15 = lane & 15, l4 = lane >> 4;
  const int m0 = blockIdx.x * 128;
  const int n0 = blockIdx.y * 128;

  floatx4 acc[4][4];
#pragma unroll
  for (int i = 0; i < 4; ++i)
#pragma unroll
    for (int j = 0; j < 4; ++j) acc[i][j] = (floatx4){0.f, 0.f, 0.f, 0.f};

  for (int k0 = 0; k0 < K_; k0 += 64) {
#pragma unroll
    for (int j = 0; j < 4; ++j) {
      const int cb = (w * 4 + j) * 64;
      const int kg = cb >> 7, rb = cb & 127;
      async16(A + (size_t)(m0 + rb + lane) * K_ + k0 + kg * 8, &sA[cb * 8]);
      async16(Bt + (size_t)(n0 + rb + lane) * K_ + k0 + kg * 8, &sB[cb * 8]);
    }
    __syncthreads();
#pragma unroll
    for (int ks = 0; ks < 2; ++ks) {
      bf16x8 af[4], bfr[4];
#pragma unroll
      for (int t = 0; t < 4; ++t)
        af[t] = *(const bf16x8*)&sA[((ks * 4 + l4) * 128 + wr + t * 16 + l15) * 8];
#pragma unroll
      for (int t = 0; t < 4; ++t)
        bfr[t] = *(const bf16x8*)&sB[((ks * 4 + l4) * 128 + wc + t * 16 + l15) * 8];
#pragma unroll
      for (int i = 0; i < 4; ++i)
#pragma unroll
        for (int j = 0; j < 4; ++j)
          acc[i][j] = __builtin_amdgcn_mfma_f32_16x16x32_bf16(af[i], bfr[j],
                                                              acc[i][j], 0, 0, 0);
    }
    __syncthreads();
  }

  if (n0 < 2 * E_) {
#pragma unroll
    for (int i = 0; i < 4; ++i)
#pragma unroll
      for (int j = 0; j < 4; ++j)
#pragma unroll
        for (int r = 0; r < 4; ++r) {
          const int row = m0 + wr + i * 16 + l4 * 4 + r;
          const int col = n0 + wc + j * 16 + l15;
          qkv[(size_t)row * N_ + col] = (bf16)acc[i][j][r];
        }
  } else {
#pragma unroll
    for (int i = 0; i < 4; ++i)
#pragma unroll
      for (int j = 0; j < 4; ++j) {
        const int f = n0 - 2 * E_ + wc + j * 16 + l15;  // 0..1023
        const int h = f >> 6, d = f & 63;
        const int row = m0 + wr + i * 16 + l4 * 4;
        const int b = row >> 11, s = row & 2047;
        bf16x4 o;
#pragma unroll
        for (int r = 0; r < 4; ++r) o[r] = (bf16)acc[i][j][r];
        *(bf16x4*)(vt + (((size_t)b * H_ + h) * D_ + d) * S_ + s) = o;
      }
  }
}

// ---------------------------------------------------------------------------
// GEMM 64x128 tile — out projection. LDS 24KB.
// ---------------------------------------------------------------------------
template <typename OutT>
__global__ __launch_bounds__(256) void gemm_bt64(
    OutT* __restrict__ C, const bf16* __restrict__ A, const bf16* __restrict__ Bt,
    int M, int N, int K) {
  __shared__ alignas(16) bf16 sA[4096];
  __shared__ alignas(16) bf16 sB[8192];
  const int tid = threadIdx.x;
  const int lane = tid & 63;
  const int w = tid >> 6;
  const int wr = (w >> 1) * 32, wc = (w & 1) * 64;
  const int l15 = lane & 15, l4 = lane >> 4;
  const int m0 = blockIdx.x * 64;
  const int n0 = blockIdx.y * 128;

  floatx4 acc[2][4];
#pragma unroll
  for (int i = 0; i < 2; ++i)
#pragma unroll
    for (int j = 0; j < 4; ++j) acc[i][j] = (floatx4){0.f, 0.f, 0.f, 0.f};

  for (int k0 = 0; k0 < K; k0 += 64) {
#pragma unroll
    for (int j = 0; j < 2; ++j) {
      const int kg = w * 2 + j;
      async16(A + (size_t)(m0 + lane) * K + k0 + kg * 8, &sA[kg * 64 * 8]);
    }
#pragma unroll
    for (int j = 0; j < 4; ++j) {
      const int cb = (w * 4 + j) * 64;
      const int kg = cb >> 7, rb = cb & 127;
      async16(Bt + (size_t)(n0 + rb + lane) * K + k0 + kg * 8, &sB[cb * 8]);
    }
    __syncthreads();
#pragma unroll
    for (int ks = 0; ks < 2; ++ks) {
      bf16x8 af[2], bfr[4];
#pragma unroll
      for (int t = 0; t < 2; ++t)
        af[t] = *(const bf16x8*)&sA[((ks * 4 + l4) * 64 + wr + t * 16 + l15) * 8];
#pragma unroll
      for (int t = 0; t < 4; ++t)
        bfr[t] = *(const bf16x8*)&sB[((ks * 4 + l4) * 128 + wc + t * 16 + l15) * 8];
#pragma unroll
      for (int i = 0; i < 2; ++i)
#pragma unroll
        for (int j = 0; j < 4; ++j)
          acc[i][j] = __builtin_amdgcn_mfma_f32_16x16x32_bf16(af[i], bfr[j],
                                                              acc[i][j], 0, 0, 0);
    }
    __syncthreads();
  }
#pragma unroll
  for (int i = 0; i < 2; ++i)
#pragma unroll
    for (int j = 0; j < 4; ++j)
#pragma unroll
      for (int r = 0; r < 4; ++r) {
        const int row = m0 + wr + i * 16 + l4 * 4 + r;
        const int col = n0 + wc + j * 16 + l15;
        C[(size_t)row * N + col] = (OutT)acc[i][j][r];
      }
}

// ---------------------------------------------------------------------------
// Flash attention v6. grid (B*H=32, S/64=32); bh on x for XCD K/V L2 reuse.
// Wave w owns q-rows [w*16,+16). Transposed scores, exp2 fixed-ref softmax.
// Pipeline: K[t] fragments prefetched into VGPRs during iter t-1 (direct
// global, L2-served); V[t] staged into LDS buffer t&1 during iter t-1.
// One __syncthreads per tile (drains both prefetches) + one wave_barrier (P).
// LDS: sV 2x16KB + sP 8KB = 40KB.
// ---------------------------------------------------------------------------
__global__ __launch_bounds__(256) void attn_flash(
    bf16* __restrict__ attn, const bf16* __restrict__ qkv,
    const bf16* __restrict__ vt) {
  __shared__ alignas(16) bf16 sV[2][8192];   // chunk (kg<16, dim<64)
  __shared__ alignas(16) bf16 sP[4][2048];   // per-wave, chunk (kg<16, ql<16)
  const int tid = threadIdx.x;
  const int lane = tid & 63;
  const int w = tid >> 6;
  const int l15 = lane & 15, l4 = lane >> 4;
  const int bh = blockIdx.x;
  const int q0 = blockIdx.y * 64;
  const int b = bh >> 4, h = bh & 15;
  const size_t row0 = (size_t)b * S_ * (3 * E_);
  const bf16* kbase = qkv + row0 + E_ + h * D_;      // K[s][d] @ kbase+s*3072+d
  const bf16* vbase = vt + (size_t)bh * D_ * S_;     // V^T[d][s]
  bf16* pq = sP[w];

  // Q fragment (B-operand), pre-scaled by log2e/sqrt(64).
  bf16x8 qf[2];
#pragma unroll
  for (int ks = 0; ks < 2; ++ks) {
    bf16x8 t = *(const bf16x8*)(qkv + row0 +
        (size_t)(q0 + w * 16 + l15) * (3 * E_) + h * D_ + ks * 32 + l4 * 8);
#pragma unroll
    for (int e = 0; e < 8; ++e)
      t[e] = (bf16)((float)t[e] * 0.180336878f);  // 0.125 * log2(e)
    qf[ks] = t;
  }

  floatx4 O[4];
#pragma unroll
  for (int j = 0; j < 4; ++j) O[j] = (floatx4){0.f, 0.f, 0.f, 0.f};
  float l_s = 0.f;

  // ---- prologue: stage V[0] into buf0; prefetch K[0] fragments ----
#pragma unroll
  for (int j = 0; j < 4; ++j)
    async16(vbase + (size_t)lane * S_ + (w * 4 + j) * 8,
            &sV[0][(w * 4 + j) * 64 * 8]);
  bf16x8 kf[2][8];  // A-operand: K[key=kt*16+l15][d=ks*32+l4*8+j]
#pragma unroll
  for (int ks = 0; ks < 2; ++ks)
#pragma unroll
    for (int kt = 0; kt < 8; ++kt)
      kf[ks][kt] = *(const bf16x8*)(kbase +
          (size_t)(kt * 16 + l15) * (3 * E_) + ks * 32 + l4 * 8);

  for (int t = 0; t < 16; ++t) {
    __syncthreads();   // V[t] staged, K[t] landed (drains all vm loads)

    const int kvn = (t + 1) * 128;
    if (t < 15) {      // stage V[t+1] into the other buffer
#pragma unroll
      for (int j = 0; j < 4; ++j)
        async16(vbase + (size_t)lane * S_ + kvn + (w * 4 + j) * 8,
                &sV[(t + 1) & 1][(w * 4 + j) * 64 * 8]);
    }

    // ---- S^T = K·Q^T, acc preloaded with -16 (softmax reference) ----
    floatx4 sc[8];
#pragma unroll
    for (int j = 0; j < 8; ++j) sc[j] = (floatx4){-16.f, -16.f, -16.f, -16.f};
#pragma unroll
    for (int ks = 0; ks < 2; ++ks)
#pragma unroll
      for (int kt = 0; kt < 8; ++kt)
        sc[kt] = __builtin_amdgcn_mfma_f32_16x16x32_bf16(
            kf[ks][kt], qf[ks], sc[kt], 0, 0, 0);

    if (t < 15) {      // prefetch K[t+1] (regs now dead; lands by next barrier)
#pragma unroll
      for (int ks = 0; ks < 2; ++ks)
#pragma unroll
        for (int kt = 0; kt < 8; ++kt)
          kf[ks][kt] = *(const bf16x8*)(kbase +
              (size_t)(kvn + kt * 16 + l15) * (3 * E_) + ks * 32 + l4 * 8);
    }

    // ---- P = exp2(sc); partial l; packed b64 stores to per-wave sP ----
    float rs = 0.f;
#pragma unroll
    for (int kt = 0; kt < 8; ++kt) {
      bf16x4 pk;
#pragma unroll
      for (int r = 0; r < 4; ++r) {
        const float p = __builtin_amdgcn_exp2f(sc[kt][r]);
        rs += p;
        pk[r] = (bf16)p;
      }
      *(bf16x4*)&pq[((2 * kt + (l4 >> 1)) * 16 + l15) * 8 + 4 * (l4 & 1)] = pk;
    }
    l_s += rs;
    __builtin_amdgcn_wave_barrier();   // per-wave sP RAW: block compiler motion

    // ---- O^T += V^T · P^T  (reads sV[t&1] + own sP) ----
    const bf16* vb = sV[t & 1];
#pragma unroll
    for (int ks = 0; ks < 4; ++ks) {
      bf16x8 pf, vf[4];
      pf = *(const bf16x8*)&pq[((ks * 4 + l4) * 16 + l15) * 8];
#pragma unroll
      for (int dt = 0; dt < 4; ++dt)
        vf[dt] = *(const bf16x8*)&vb[((ks * 4 + l4) * 64 + dt * 16 + l15) * 8];
#pragma unroll
      for (int dt = 0; dt < 4; ++dt)
        O[dt] = __builtin_amdgcn_mfma_f32_16x16x32_bf16(vf[dt], pf, O[dt], 0, 0, 0);
    }
    // no trailing barrier: next iter's syncthreads separates PV(t) from
    // staging that targets buf[t&1] (issued at iter t+1 for tile t+2).
  }

  // epilogue: reduce l across l4 (keys partitioned by l4), scale, store
  float l = l_s;
  l += __shfl_xor(l, 16);
  l += __shfl_xor(l, 32);
  const float inv_l = 1.f / l;
  const int row = q0 + w * 16 + l15;
#pragma unroll
  for (int dt = 0; dt < 4; ++dt) {
    bf16x4 o;
#pragma unroll
    for (int r = 0; r < 4; ++r) o[r] = (bf16)(O[dt][r] * inv_l);
    *(bf16x4*)(attn + ((size_t)b * S_ + row) * E_ + h * D_ + dt * 16 + l4 * 4) = o;
  }
}

// ---------------------------------------------------------------------------
extern "C" void kernel_launch(void* const* d_in, const int* in_sizes, int n_in,
                              void* d_out, int out_size, void* d_ws, size_t ws_size,
                              hipStream_t stream) {
  const float* x = (const float*)d_in[0];      // (B,S,E) fp32
  const float* wqkv = (const float*)d_in[1];   // (E,3E)  fp32
  const float* wout = (const float*)d_in[2];   // (E,E)   fp32
  float* out = (float*)d_out;                  // (B,S,E) fp32

  bf16* ws = (bf16*)d_ws;
  bf16* xb = ws;                                    // 4096 x 1024
  bf16* qkv = xb + (size_t)4096 * 1024;             // 4096 x 3072 (Q,K used)
  bf16* wqkvT = qkv + (size_t)4096 * 3072;          // 3072 x 1024
  bf16* woutT = wqkvT + (size_t)3072 * 1024;        // 1024 x 1024
  bf16* vt = woutT + (size_t)1024 * 1024;           // (B*H) x 64 x 2048
  bf16* attn = vt + (size_t)B_ * H_ * D_ * S_;      // 4096 x 1024

  prep<<<dim3(8192), 256, 0, stream>>>(xb, wqkvT, woutT, x, wqkv, wout);
  gemm_qkv<<<dim3(32, 24), 256, 0, stream>>>(qkv, vt, xb, wqkvT);
  attn_flash<<<dim3(B_ * H_, S_ / 64), 256, 0, stream>>>(attn, qkv, vt);
  gemm_bt64<float><<<dim3(64, 8), 256, 0, stream>>>(out, attn, woutT, 4096, E_, E_);
}

// Round 11
// 251.871 us; speedup vs baseline: 1.2709x; 1.2709x over previous
//
#include <hip/hip_runtime.h>
#include <cstdint>

// Multihead self-attention, B=2 S=2048 E=1024 H=16 D=64.
// fp32 in/out; internal bf16 MFMA, fp32 accum.
// R11: attn = R9 structure (async16 K+V staging, 64 VGPR, transposed scores,
// exp2 fixed-ref softmax, P overlays K buffer) + double-buffered STAGING:
// stage(t+1) issued right after syncA(t) so the vm drain at syncA(t+1) is
// covered by a full tile of compute. 2 syncthreads + 1 wave_barrier per tile.
// LDS 64KB -> 2 blocks/CU resident. R10's K-in-VGPR prefetch reverted.

typedef __bf16 bf16;
typedef __bf16 bf16x4 __attribute__((ext_vector_type(4)));
typedef __bf16 bf16x8 __attribute__((ext_vector_type(8)));
typedef float floatx4 __attribute__((ext_vector_type(4)));
typedef uint32_t u32;

#define B_ 2
#define S_ 2048
#define E_ 1024
#define H_ 16
#define D_ 64

__device__ __forceinline__ void async16(const void* g, const void* l) {
  __builtin_amdgcn_global_load_lds(
      (u32 __attribute__((address_space(1)))*)g,
      (u32 __attribute__((address_space(3)))*)l,
      16, 0, 0);
}

// ---------------------------------------------------------------------------
// prep: blockIdx.x < 3072  -> transpose+cvt wqkv (1024x3072 -> 3072x1024 bf16)
//       3072..4095         -> transpose+cvt wout (1024x1024)
//       4096..8191         -> x fp32 -> bf16 elementwise
// ---------------------------------------------------------------------------
__device__ __forceinline__ void trans_tile(
    bf16* __restrict__ dst, const float* __restrict__ src, int R, int C,
    int c0, int r0, float (*t)[33]) {
  const int tx = threadIdx.x & 31, ty = threadIdx.x >> 5;
#pragma unroll
  for (int j = 0; j < 4; ++j)
    t[ty + 8 * j][tx] = src[(size_t)(r0 + ty + 8 * j) * C + c0 + tx];
  __syncthreads();
#pragma unroll
  for (int j = 0; j < 4; ++j)
    dst[(size_t)(c0 + ty + 8 * j) * R + r0 + tx] = (bf16)t[tx][ty + 8 * j];
}

__global__ __launch_bounds__(256) void prep(
    bf16* __restrict__ xb, bf16* __restrict__ wqkvT, bf16* __restrict__ woutT,
    const float* __restrict__ x, const float* __restrict__ wqkv,
    const float* __restrict__ wout) {
  __shared__ float t[32][33];
  const int id = blockIdx.x;
  if (id < 3072) {
    trans_tile(wqkvT, wqkv, 1024, 3072, (id % 96) * 32, (id / 96) * 32, t);
  } else if (id < 4096) {
    const int i2 = id - 3072;
    trans_tile(woutT, wout, 1024, 1024, (i2 % 32) * 32, (i2 / 32) * 32, t);
  } else {
    const int i = (id - 4096) * 256 + threadIdx.x;  // floatx4 index, exact fit
    floatx4 v = ((const floatx4*)x)[i];
    bf16x4 o;
#pragma unroll
    for (int e = 0; e < 4; ++e) o[e] = (bf16)v[e];
    ((bf16x4*)xb)[i] = o;
  }
}

// ---------------------------------------------------------------------------
// QKV GEMM, 128x128 tile (m97 structure). M=4096, N=3072, K=1024.
// n0<2048 (Q,K) -> qkv rows; n0>=2048 (V) -> vt transposed (repack fused).
// ---------------------------------------------------------------------------
__global__ __launch_bounds__(256) void gemm_qkv(
    bf16* __restrict__ qkv, bf16* __restrict__ vt,
    const bf16* __restrict__ A, const bf16* __restrict__ Bt) {
  const int N_ = 3072, K_ = 1024;
  __shared__ alignas(16) bf16 sA[8192];
  __shared__ alignas(16) bf16 sB[8192];
  const int tid = threadIdx.x;
  const int lane = tid & 63;
  const int w = tid >> 6;
  const int wr = (w >> 1) * 64, wc = (w & 1) * 64;
  const int l15 = lane & 15, l4 = lane >> 4;
  const int m0 = blockIdx.x * 128;
  const int n0 = blockIdx.y * 128;

  floatx4 acc[4][4];
#pragma unroll
  for (int i = 0; i < 4; ++i)
#pragma unroll
    for (int j = 0; j < 4; ++j) acc[i][j] = (floatx4){0.f, 0.f, 0.f, 0.f};

  for (int k0 = 0; k0 < K_; k0 += 64) {
#pragma unroll
    for (int j = 0; j < 4; ++j) {
      const int cb = (w * 4 + j) * 64;
      const int kg = cb >> 7, rb = cb & 127;
      async16(A + (size_t)(m0 + rb + lane) * K_ + k0 + kg * 8, &sA[cb * 8]);
      async16(Bt + (size_t)(n0 + rb + lane) * K_ + k0 + kg * 8, &sB[cb * 8]);
    }
    __syncthreads();
#pragma unroll
    for (int ks = 0; ks < 2; ++ks) {
      bf16x8 af[4], bfr[4];
#pragma unroll
      for (int t = 0; t < 4; ++t)
        af[t] = *(const bf16x8*)&sA[((ks * 4 + l4) * 128 + wr + t * 16 + l15) * 8];
#pragma unroll
      for (int t = 0; t < 4; ++t)
        bfr[t] = *(const bf16x8*)&sB[((ks * 4 + l4) * 128 + wc + t * 16 + l15) * 8];
#pragma unroll
      for (int i = 0; i < 4; ++i)
#pragma unroll
        for (int j = 0; j < 4; ++j)
          acc[i][j] = __builtin_amdgcn_mfma_f32_16x16x32_bf16(af[i], bfr[j],
                                                              acc[i][j], 0, 0, 0);
    }
    __syncthreads();
  }

  if (n0 < 2 * E_) {
#pragma unroll
    for (int i = 0; i < 4; ++i)
#pragma unroll
      for (int j = 0; j < 4; ++j)
#pragma unroll
        for (int r = 0; r < 4; ++r) {
          const int row = m0 + wr + i * 16 + l4 * 4 + r;
          const int col = n0 + wc + j * 16 + l15;
          qkv[(size_t)row * N_ + col] = (bf16)acc[i][j][r];
        }
  } else {
#pragma unroll
    for (int i = 0; i < 4; ++i)
#pragma unroll
      for (int j = 0; j < 4; ++j) {
        const int f = n0 - 2 * E_ + wc + j * 16 + l15;  // 0..1023
        const int h = f >> 6, d = f & 63;
        const int row = m0 + wr + i * 16 + l4 * 4;
        const int b = row >> 11, s = row & 2047;
        bf16x4 o;
#pragma unroll
        for (int r = 0; r < 4; ++r) o[r] = (bf16)acc[i][j][r];
        *(bf16x4*)(vt + (((size_t)b * H_ + h) * D_ + d) * S_ + s) = o;
      }
  }
}

// ---------------------------------------------------------------------------
// GEMM 64x128 tile — out projection. LDS 24KB.
// ---------------------------------------------------------------------------
template <typename OutT>
__global__ __launch_bounds__(256) void gemm_bt64(
    OutT* __restrict__ C, const bf16* __restrict__ A, const bf16* __restrict__ Bt,
    int M, int N, int K) {
  __shared__ alignas(16) bf16 sA[4096];
  __shared__ alignas(16) bf16 sB[8192];
  const int tid = threadIdx.x;
  const int lane = tid & 63;
  const int w = tid >> 6;
  const int wr = (w >> 1) * 32, wc = (w & 1) * 64;
  const int l15 = lane & 15, l4 = lane >> 4;
  const int m0 = blockIdx.x * 64;
  const int n0 = blockIdx.y * 128;

  floatx4 acc[2][4];
#pragma unroll
  for (int i = 0; i < 2; ++i)
#pragma unroll
    for (int j = 0; j < 4; ++j) acc[i][j] = (floatx4){0.f, 0.f, 0.f, 0.f};

  for (int k0 = 0; k0 < K; k0 += 64) {
#pragma unroll
    for (int j = 0; j < 2; ++j) {
      const int kg = w * 2 + j;
      async16(A + (size_t)(m0 + lane) * K + k0 + kg * 8, &sA[kg * 64 * 8]);
    }
#pragma unroll
    for (int j = 0; j < 4; ++j) {
      const int cb = (w * 4 + j) * 64;
      const int kg = cb >> 7, rb = cb & 127;
      async16(Bt + (size_t)(n0 + rb + lane) * K + k0 + kg * 8, &sB[cb * 8]);
    }
    __syncthreads();
#pragma unroll
    for (int ks = 0; ks < 2; ++ks) {
      bf16x8 af[2], bfr[4];
#pragma unroll
      for (int t = 0; t < 2; ++t)
        af[t] = *(const bf16x8*)&sA[((ks * 4 + l4) * 64 + wr + t * 16 + l15) * 8];
#pragma unroll
      for (int t = 0; t < 4; ++t)
        bfr[t] = *(const bf16x8*)&sB[((ks * 4 + l4) * 128 + wc + t * 16 + l15) * 8];
#pragma unroll
      for (int i = 0; i < 2; ++i)
#pragma unroll
        for (int j = 0; j < 4; ++j)
          acc[i][j] = __builtin_amdgcn_mfma_f32_16x16x32_bf16(af[i], bfr[j],
                                                              acc[i][j], 0, 0, 0);
    }
    __syncthreads();
  }
#pragma unroll
  for (int i = 0; i < 2; ++i)
#pragma unroll
    for (int j = 0; j < 4; ++j)
#pragma unroll
      for (int r = 0; r < 4; ++r) {
        const int row = m0 + wr + i * 16 + l4 * 4 + r;
        const int col = n0 + wc + j * 16 + l15;
        C[(size_t)row * N + col] = (OutT)acc[i][j][r];
      }
}

// ---------------------------------------------------------------------------
// Flash attention v7. grid (B*H=32, S/64=32); bh on x for XCD K/V L2 reuse.
// Wave w owns q-rows [w*16,+16). Transposed scores, exp2 fixed-ref softmax.
// Double-buffered STAGING: stage(t+1) via async16 is issued right after
// syncA(t), so its drain at syncA(t+1) has a full tile of compute behind it.
// Safety: PV(t-1)'s reads of buf[(t-1)&1] precede syncA(t) in program order,
// so post-syncA staging into buf[(t+1)&1] (same buffer) cannot race.
// P overlays wave w's quarter of the CURRENT K buffer after syncB.
// LDS: 2*(sK 16 + sV 16) = 64KB -> 2 blocks/CU. VGPR ~64 (no K prefetch regs).
// ---------------------------------------------------------------------------
__global__ __launch_bounds__(256) void attn_flash(
    bf16* __restrict__ attn, const bf16* __restrict__ qkv,
    const bf16* __restrict__ vt) {
  __shared__ alignas(16) bf16 sK[2][8192];   // chunk (kg<8, key<128)
  __shared__ alignas(16) bf16 sV[2][8192];   // chunk (kg<16, dim<64)
  const int tid = threadIdx.x;
  const int lane = tid & 63;
  const int w = tid >> 6;
  const int l15 = lane & 15, l4 = lane >> 4;
  const int bh = blockIdx.x;
  const int q0 = blockIdx.y * 64;
  const int b = bh >> 4, h = bh & 15;
  const size_t row0 = (size_t)b * S_ * (3 * E_);
  const bf16* vbase = vt + (size_t)bh * D_ * S_;   // V^T[d][s]

  // Q fragment (B-operand), pre-scaled by log2e/sqrt(64).
  bf16x8 qf[2];
#pragma unroll
  for (int ks = 0; ks < 2; ++ks) {
    bf16x8 t = *(const bf16x8*)(qkv + row0 +
        (size_t)(q0 + w * 16 + l15) * (3 * E_) + h * D_ + ks * 32 + l4 * 8);
#pragma unroll
    for (int e = 0; e < 8; ++e)
      t[e] = (bf16)((float)t[e] * 0.180336878f);  // 0.125 * log2(e)
    qf[ks] = t;
  }

  floatx4 O[4];
#pragma unroll
  for (int j = 0; j < 4; ++j) O[j] = (floatx4){0.f, 0.f, 0.f, 0.f};
  float l_s = 0.f;

  // ---- prologue: stage tile 0 into buffer 0 ----
#pragma unroll
  for (int j = 0; j < 4; ++j) {
    const int cb = (w * 4 + j) * 64;
    async16(qkv + row0 + (size_t)((cb & 127) + lane) * (3 * E_) +
                E_ + h * D_ + (cb >> 7) * 8,
            &sK[0][cb * 8]);
    async16(vbase + (size_t)lane * S_ + (w * 4 + j) * 8, &sV[0][cb * 8]);
  }

  for (int t = 0; t < 16; ++t) {
    const int cur = t & 1, nxt = cur ^ 1;
    __syncthreads();   // A: stage(t) drained; PV(t-1) reads of buf nxt done

    if (t < 15) {      // stage tile t+1 into the other buffer (fire & forget)
      const int kvn = (t + 1) * 128;
#pragma unroll
      for (int j = 0; j < 4; ++j) {
        const int cb = (w * 4 + j) * 64;
        async16(qkv + row0 + (size_t)(kvn + (cb & 127) + lane) * (3 * E_) +
                    E_ + h * D_ + (cb >> 7) * 8,
                &sK[nxt][cb * 8]);
        async16(vbase + (size_t)lane * S_ + kvn + (w * 4 + j) * 8,
                &sV[nxt][cb * 8]);
      }
    }

    // ---- S^T = K·Q^T, acc preloaded with -16 (softmax reference) ----
    floatx4 sc[8];
#pragma unroll
    for (int j = 0; j < 8; ++j) sc[j] = (floatx4){-16.f, -16.f, -16.f, -16.f};
#pragma unroll
    for (int ks = 0; ks < 2; ++ks) {
      bf16x8 kf[8];
#pragma unroll
      for (int kt = 0; kt < 8; ++kt)
        kf[kt] = *(const bf16x8*)&sK[cur][((ks * 4 + l4) * 128 + kt * 16 + l15) * 8];
#pragma unroll
      for (int kt = 0; kt < 8; ++kt)
        sc[kt] = __builtin_amdgcn_mfma_f32_16x16x32_bf16(
            kf[kt], qf[ks], sc[kt], 0, 0, 0);
    }
    __syncthreads();   // B: all waves done reading sK[cur] -> P may overlay

    // ---- P = exp2(sc); per-lane partial l; packed b64 to own quarter ----
    bf16* pq = &sK[cur][w * 2048];
    float rs = 0.f;
#pragma unroll
    for (int kt = 0; kt < 8; ++kt) {
      bf16x4 pk;
#pragma unroll
      for (int r = 0; r < 4; ++r) {
        const float p = __builtin_amdgcn_exp2f(sc[kt][r]);
        rs += p;
        pk[r] = (bf16)p;
      }
      *(bf16x4*)&pq[((2 * kt + (l4 >> 1)) * 16 + l15) * 8 + 4 * (l4 & 1)] = pk;
    }
    l_s += rs;
    __builtin_amdgcn_wave_barrier();   // own-quarter RAW: block compiler motion

    // ---- O^T += V^T · P^T ----
#pragma unroll
    for (int ks = 0; ks < 4; ++ks) {
      bf16x8 pf, vf[4];
      pf = *(const bf16x8*)&pq[((ks * 4 + l4) * 16 + l15) * 8];
#pragma unroll
      for (int dt = 0; dt < 4; ++dt)
        vf[dt] = *(const bf16x8*)&sV[cur][((ks * 4 + l4) * 64 + dt * 16 + l15) * 8];
#pragma unroll
      for (int dt = 0; dt < 4; ++dt)
        O[dt] = __builtin_amdgcn_mfma_f32_16x16x32_bf16(vf[dt], pf, O[dt], 0, 0, 0);
    }
    // next iteration's syncA orders these PV reads before staging reuses bufs
  }

  // epilogue: reduce l across l4 (keys partitioned by l4), scale, store
  float l = l_s;
  l += __shfl_xor(l, 16);
  l += __shfl_xor(l, 32);
  const float inv_l = 1.f / l;
  const int row = q0 + w * 16 + l15;
#pragma unroll
  for (int dt = 0; dt < 4; ++dt) {
    bf16x4 o;
#pragma unroll
    for (int r = 0; r < 4; ++r) o[r] = (bf16)(O[dt][r] * inv_l);
    *(bf16x4*)(attn + ((size_t)b * S_ + row) * E_ + h * D_ + dt * 16 + l4 * 4) = o;
  }
}

// ---------------------------------------------------------------------------
extern "C" void kernel_launch(void* const* d_in, const int* in_sizes, int n_in,
                              void* d_out, int out_size, void* d_ws, size_t ws_size,
                              hipStream_t stream) {
  const float* x = (const float*)d_in[0];      // (B,S,E) fp32
  const float* wqkv = (const float*)d_in[1];   // (E,3E)  fp32
  const float* wout = (const float*)d_in[2];   // (E,E)   fp32
  float* out = (float*)d_out;                  // (B,S,E) fp32

  bf16* ws = (bf16*)d_ws;
  bf16* xb = ws;                                    // 4096 x 1024
  bf16* qkv = xb + (size_t)4096 * 1024;             // 4096 x 3072 (Q,K used)
  bf16* wqkvT = qkv + (size_t)4096 * 3072;          // 3072 x 1024
  bf16* woutT = wqkvT + (size_t)3072 * 1024;        // 1024 x 1024
  bf16* vt = woutT + (size_t)1024 * 1024;           // (B*H) x 64 x 2048
  bf16* attn = vt + (size_t)B_ * H_ * D_ * S_;      // 4096 x 1024

  prep<<<dim3(8192), 256, 0, stream>>>(xb, wqkvT, woutT, x, wqkv, wout);
  gemm_qkv<<<dim3(32, 24), 256, 0, stream>>>(qkv, vt, xb, wqkvT);
  attn_flash<<<dim3(B_ * H_, S_ / 64), 256, 0, stream>>>(attn, qkv, vt);
  gemm_bt64<float><<<dim3(64, 8), 256, 0, stream>>>(out, attn, woutT, 4096, E_, E_);
}

// Round 12
// 234.656 us; speedup vs baseline: 1.3642x; 1.0734x over previous
//
#include <hip/hip_runtime.h>
#include <cstdint>

// Multihead self-attention, B=2 S=2048 E=1024 H=16 D=64.
// fp32 in/out; internal bf16 MFMA, fp32 accum.
// R12: attn — TRUE 1-barrier pipeline: 64-key KV tiles, double-buffered
// sK/sV, separate per-wave sP (no overlay -> no syncB). stage(t+1) issued
// right after the single syncthreads, consumed at the next one with a full
// tile of compute cover. LDS 40KB -> 4 blocks/CU. GEMMs/prep unchanged.

typedef __bf16 bf16;
typedef __bf16 bf16x4 __attribute__((ext_vector_type(4)));
typedef __bf16 bf16x8 __attribute__((ext_vector_type(8)));
typedef float floatx4 __attribute__((ext_vector_type(4)));
typedef uint32_t u32;

#define B_ 2
#define S_ 2048
#define E_ 1024
#define H_ 16
#define D_ 64

__device__ __forceinline__ void async16(const void* g, const void* l) {
  __builtin_amdgcn_global_load_lds(
      (u32 __attribute__((address_space(1)))*)g,
      (u32 __attribute__((address_space(3)))*)l,
      16, 0, 0);
}

// ---------------------------------------------------------------------------
// prep: blockIdx.x < 3072  -> transpose+cvt wqkv; 3072..4095 -> wout;
//       4096..8191 -> x fp32 -> bf16 elementwise
// ---------------------------------------------------------------------------
__device__ __forceinline__ void trans_tile(
    bf16* __restrict__ dst, const float* __restrict__ src, int R, int C,
    int c0, int r0, float (*t)[33]) {
  const int tx = threadIdx.x & 31, ty = threadIdx.x >> 5;
#pragma unroll
  for (int j = 0; j < 4; ++j)
    t[ty + 8 * j][tx] = src[(size_t)(r0 + ty + 8 * j) * C + c0 + tx];
  __syncthreads();
#pragma unroll
  for (int j = 0; j < 4; ++j)
    dst[(size_t)(c0 + ty + 8 * j) * R + r0 + tx] = (bf16)t[tx][ty + 8 * j];
}

__global__ __launch_bounds__(256) void prep(
    bf16* __restrict__ xb, bf16* __restrict__ wqkvT, bf16* __restrict__ woutT,
    const float* __restrict__ x, const float* __restrict__ wqkv,
    const float* __restrict__ wout) {
  __shared__ float t[32][33];
  const int id = blockIdx.x;
  if (id < 3072) {
    trans_tile(wqkvT, wqkv, 1024, 3072, (id % 96) * 32, (id / 96) * 32, t);
  } else if (id < 4096) {
    const int i2 = id - 3072;
    trans_tile(woutT, wout, 1024, 1024, (i2 % 32) * 32, (i2 / 32) * 32, t);
  } else {
    const int i = (id - 4096) * 256 + threadIdx.x;
    floatx4 v = ((const floatx4*)x)[i];
    bf16x4 o;
#pragma unroll
    for (int e = 0; e < 4; ++e) o[e] = (bf16)v[e];
    ((bf16x4*)xb)[i] = o;
  }
}

// ---------------------------------------------------------------------------
// QKV GEMM, 128x128 tile (m97 structure). M=4096, N=3072, K=1024.
// n0<2048 (Q,K) -> qkv rows; n0>=2048 (V) -> vt transposed (repack fused).
// ---------------------------------------------------------------------------
__global__ __launch_bounds__(256) void gemm_qkv(
    bf16* __restrict__ qkv, bf16* __restrict__ vt,
    const bf16* __restrict__ A, const bf16* __restrict__ Bt) {
  const int N_ = 3072, K_ = 1024;
  __shared__ alignas(16) bf16 sA[8192];
  __shared__ alignas(16) bf16 sB[8192];
  const int tid = threadIdx.x;
  const int lane = tid & 63;
  const int w = tid >> 6;
  const int wr = (w >> 1) * 64, wc = (w & 1) * 64;
  const int l15 = lane & 15, l4 = lane >> 4;
  const int m0 = blockIdx.x * 128;
  const int n0 = blockIdx.y * 128;

  floatx4 acc[4][4];
#pragma unroll
  for (int i = 0; i < 4; ++i)
#pragma unroll
    for (int j = 0; j < 4; ++j) acc[i][j] = (floatx4){0.f, 0.f, 0.f, 0.f};

  for (int k0 = 0; k0 < K_; k0 += 64) {
#pragma unroll
    for (int j = 0; j < 4; ++j) {
      const int cb = (w * 4 + j) * 64;
      const int kg = cb >> 7, rb = cb & 127;
      async16(A + (size_t)(m0 + rb + lane) * K_ + k0 + kg * 8, &sA[cb * 8]);
      async16(Bt + (size_t)(n0 + rb + lane) * K_ + k0 + kg * 8, &sB[cb * 8]);
    }
    __syncthreads();
#pragma unroll
    for (int ks = 0; ks < 2; ++ks) {
      bf16x8 af[4], bfr[4];
#pragma unroll
      for (int t = 0; t < 4; ++t)
        af[t] = *(const bf16x8*)&sA[((ks * 4 + l4) * 128 + wr + t * 16 + l15) * 8];
#pragma unroll
      for (int t = 0; t < 4; ++t)
        bfr[t] = *(const bf16x8*)&sB[((ks * 4 + l4) * 128 + wc + t * 16 + l15) * 8];
#pragma unroll
      for (int i = 0; i < 4; ++i)
#pragma unroll
        for (int j = 0; j < 4; ++j)
          acc[i][j] = __builtin_amdgcn_mfma_f32_16x16x32_bf16(af[i], bfr[j],
                                                              acc[i][j], 0, 0, 0);
    }
    __syncthreads();
  }

  if (n0 < 2 * E_) {
#pragma unroll
    for (int i = 0; i < 4; ++i)
#pragma unroll
      for (int j = 0; j < 4; ++j)
#pragma unroll
        for (int r = 0; r < 4; ++r) {
          const int row = m0 + wr + i * 16 + l4 * 4 + r;
          const int col = n0 + wc + j * 16 + l15;
          qkv[(size_t)row * N_ + col] = (bf16)acc[i][j][r];
        }
  } else {
#pragma unroll
    for (int i = 0; i < 4; ++i)
#pragma unroll
      for (int j = 0; j < 4; ++j) {
        const int f = n0 - 2 * E_ + wc + j * 16 + l15;  // 0..1023
        const int h = f >> 6, d = f & 63;
        const int row = m0 + wr + i * 16 + l4 * 4;
        const int b = row >> 11, s = row & 2047;
        bf16x4 o;
#pragma unroll
        for (int r = 0; r < 4; ++r) o[r] = (bf16)acc[i][j][r];
        *(bf16x4*)(vt + (((size_t)b * H_ + h) * D_ + d) * S_ + s) = o;
      }
  }
}

// ---------------------------------------------------------------------------
// GEMM 64x128 tile — out projection. LDS 24KB.
// ---------------------------------------------------------------------------
template <typename OutT>
__global__ __launch_bounds__(256) void gemm_bt64(
    OutT* __restrict__ C, const bf16* __restrict__ A, const bf16* __restrict__ Bt,
    int M, int N, int K) {
  __shared__ alignas(16) bf16 sA[4096];
  __shared__ alignas(16) bf16 sB[8192];
  const int tid = threadIdx.x;
  const int lane = tid & 63;
  const int w = tid >> 6;
  const int wr = (w >> 1) * 32, wc = (w & 1) * 64;
  const int l15 = lane & 15, l4 = lane >> 4;
  const int m0 = blockIdx.x * 64;
  const int n0 = blockIdx.y * 128;

  floatx4 acc[2][4];
#pragma unroll
  for (int i = 0; i < 2; ++i)
#pragma unroll
    for (int j = 0; j < 4; ++j) acc[i][j] = (floatx4){0.f, 0.f, 0.f, 0.f};

  for (int k0 = 0; k0 < K; k0 += 64) {
#pragma unroll
    for (int j = 0; j < 2; ++j) {
      const int kg = w * 2 + j;
      async16(A + (size_t)(m0 + lane) * K + k0 + kg * 8, &sA[kg * 64 * 8]);
    }
#pragma unroll
    for (int j = 0; j < 4; ++j) {
      const int cb = (w * 4 + j) * 64;
      const int kg = cb >> 7, rb = cb & 127;
      async16(Bt + (size_t)(n0 + rb + lane) * K + k0 + kg * 8, &sB[cb * 8]);
    }
    __syncthreads();
#pragma unroll
    for (int ks = 0; ks < 2; ++ks) {
      bf16x8 af[2], bfr[4];
#pragma unroll
      for (int t = 0; t < 2; ++t)
        af[t] = *(const bf16x8*)&sA[((ks * 4 + l4) * 64 + wr + t * 16 + l15) * 8];
#pragma unroll
      for (int t = 0; t < 4; ++t)
        bfr[t] = *(const bf16x8*)&sB[((ks * 4 + l4) * 128 + wc + t * 16 + l15) * 8];
#pragma unroll
      for (int i = 0; i < 2; ++i)
#pragma unroll
        for (int j = 0; j < 4; ++j)
          acc[i][j] = __builtin_amdgcn_mfma_f32_16x16x32_bf16(af[i], bfr[j],
                                                              acc[i][j], 0, 0, 0);
    }
    __syncthreads();
  }
#pragma unroll
  for (int i = 0; i < 2; ++i)
#pragma unroll
    for (int j = 0; j < 4; ++j)
#pragma unroll
      for (int r = 0; r < 4; ++r) {
        const int row = m0 + wr + i * 16 + l4 * 4 + r;
        const int col = n0 + wc + j * 16 + l15;
        C[(size_t)row * N + col] = (OutT)acc[i][j][r];
      }
}

// ---------------------------------------------------------------------------
// Flash attention v8. grid (B*H=32, S/64=32); bh on x for XCD K/V L2 reuse.
// Wave w owns q-rows [w*16,+16). Transposed scores, exp2 fixed-ref softmax.
// 64-key KV tiles (32 tiles), double-buffered sK/sV, separate per-wave sP.
// ONE __syncthreads per tile; stage(t+1) issued right after it -> full-tile
// latency cover at the next barrier. Plus one wave_barrier for the P RAW.
// LDS: 2*8 (sK) + 2*8 (sV) + 8 (sP) = 40KB -> 4 blocks/CU.
// ---------------------------------------------------------------------------
__global__ __launch_bounds__(256) void attn_flash(
    bf16* __restrict__ attn, const bf16* __restrict__ qkv,
    const bf16* __restrict__ vt) {
  __shared__ alignas(16) bf16 sK[2][4096];   // chunk (kg<8, key<64)
  __shared__ alignas(16) bf16 sV[2][4096];   // chunk (kg<8, dim<64)
  __shared__ alignas(16) bf16 sP[4][1024];   // per-wave, chunk (kg<8, ql<16)
  const int tid = threadIdx.x;
  const int lane = tid & 63;
  const int w = tid >> 6;
  const int l15 = lane & 15, l4 = lane >> 4;
  const int bh = blockIdx.x;
  const int q0 = blockIdx.y * 64;
  const int b = bh >> 4, h = bh & 15;
  const size_t row0 = (size_t)b * S_ * (3 * E_);
  const bf16* kbase = qkv + row0 + E_ + h * D_;    // K[s][d] @ kbase+s*3072+d
  const bf16* vbase = vt + (size_t)bh * D_ * S_;   // V^T[d][s]
  bf16* pq = sP[w];

  // Q fragment (B-operand), pre-scaled by log2e/sqrt(64).
  bf16x8 qf[2];
#pragma unroll
  for (int ks = 0; ks < 2; ++ks) {
    bf16x8 t = *(const bf16x8*)(qkv + row0 +
        (size_t)(q0 + w * 16 + l15) * (3 * E_) + h * D_ + ks * 32 + l4 * 8);
#pragma unroll
    for (int e = 0; e < 8; ++e)
      t[e] = (bf16)((float)t[e] * 0.180336878f);  // 0.125 * log2(e)
    qf[ks] = t;
  }

  floatx4 O[4];
#pragma unroll
  for (int j = 0; j < 4; ++j) O[j] = (floatx4){0.f, 0.f, 0.f, 0.f};
  float l_s = 0.f;

  // ---- prologue: stage tile 0 into buffer 0 (2 K + 2 V async16 per wave) --
#pragma unroll
  for (int j = 0; j < 2; ++j) {
    const int kg = w * 2 + j;
    async16(kbase + (size_t)lane * (3 * E_) + kg * 8, &sK[0][(kg * 64 + lane) * 8]);
    async16(vbase + (size_t)lane * S_ + kg * 8, &sV[0][(kg * 64 + lane) * 8]);
  }

  for (int t = 0; t < 32; ++t) {
    const int cur = t & 1, nxt = cur ^ 1;
    __syncthreads();   // drains stage(t) — covered by tile t-1's compute

    if (t < 31) {      // stage tile t+1 into the other buffer
      const int kvn = (t + 1) * 64;
#pragma unroll
      for (int j = 0; j < 2; ++j) {
        const int kg = w * 2 + j;
        async16(kbase + (size_t)(kvn + lane) * (3 * E_) + kg * 8,
                &sK[nxt][(kg * 64 + lane) * 8]);
        async16(vbase + (size_t)lane * S_ + kvn + kg * 8,
                &sV[nxt][(kg * 64 + lane) * 8]);
      }
    }

    // ---- S^T = K·Q^T : sc[kt], key = kt*16 + l4*4 + r, q = l15 ----
    floatx4 sc[4];
#pragma unroll
    for (int j = 0; j < 4; ++j) sc[j] = (floatx4){-16.f, -16.f, -16.f, -16.f};
#pragma unroll
    for (int ks = 0; ks < 2; ++ks) {
      bf16x8 kf[4];  // A-operand: K[key=kt*16+l15][d=ks*32+l4*8+j]
#pragma unroll
      for (int kt = 0; kt < 4; ++kt)
        kf[kt] = *(const bf16x8*)&sK[cur][((ks * 4 + l4) * 64 + kt * 16 + l15) * 8];
#pragma unroll
      for (int kt = 0; kt < 4; ++kt)
        sc[kt] = __builtin_amdgcn_mfma_f32_16x16x32_bf16(
            kf[kt], qf[ks], sc[kt], 0, 0, 0);
    }

    // ---- P = exp2(sc); per-lane partial l; packed b64 to per-wave sP ----
    float rs = 0.f;
#pragma unroll
    for (int kt = 0; kt < 4; ++kt) {
      bf16x4 pk;
#pragma unroll
      for (int r = 0; r < 4; ++r) {
        const float p = __builtin_amdgcn_exp2f(sc[kt][r]);
        rs += p;
        pk[r] = (bf16)p;
      }
      *(bf16x4*)&pq[((2 * kt + (l4 >> 1)) * 16 + l15) * 8 + 4 * (l4 & 1)] = pk;
    }
    l_s += rs;
    __builtin_amdgcn_wave_barrier();   // own-region RAW: block compiler motion

    // ---- O^T += V^T · P^T ----
#pragma unroll
    for (int ks = 0; ks < 2; ++ks) {
      bf16x8 pf, vf[4];
      pf = *(const bf16x8*)&pq[((ks * 4 + l4) * 16 + l15) * 8];
#pragma unroll
      for (int dt = 0; dt < 4; ++dt)
        vf[dt] = *(const bf16x8*)&sV[cur][((ks * 4 + l4) * 64 + dt * 16 + l15) * 8];
#pragma unroll
      for (int dt = 0; dt < 4; ++dt)
        O[dt] = __builtin_amdgcn_mfma_f32_16x16x32_bf16(vf[dt], pf, O[dt], 0, 0, 0);
    }
    // next iteration's syncthreads orders these reads before buffer reuse
  }

  // epilogue: reduce l across l4 (keys partitioned by l4), scale, store
  float l = l_s;
  l += __shfl_xor(l, 16);
  l += __shfl_xor(l, 32);
  const float inv_l = 1.f / l;
  const int row = q0 + w * 16 + l15;
#pragma unroll
  for (int dt = 0; dt < 4; ++dt) {
    bf16x4 o;
#pragma unroll
    for (int r = 0; r < 4; ++r) o[r] = (bf16)(O[dt][r] * inv_l);
    *(bf16x4*)(attn + ((size_t)b * S_ + row) * E_ + h * D_ + dt * 16 + l4 * 4) = o;
  }
}

// ---------------------------------------------------------------------------
extern "C" void kernel_launch(void* const* d_in, const int* in_sizes, int n_in,
                              void* d_out, int out_size, void* d_ws, size_t ws_size,
                              hipStream_t stream) {
  const float* x = (const float*)d_in[0];      // (B,S,E) fp32
  const float* wqkv = (const float*)d_in[1];   // (E,3E)  fp32
  const float* wout = (const float*)d_in[2];   // (E,E)   fp32
  float* out = (float*)d_out;                  // (B,S,E) fp32

  bf16* ws = (bf16*)d_ws;
  bf16* xb = ws;                                    // 4096 x 1024
  bf16* qkv = xb + (size_t)4096 * 1024;             // 4096 x 3072 (Q,K used)
  bf16* wqkvT = qkv + (size_t)4096 * 3072;          // 3072 x 1024
  bf16* woutT = wqkvT + (size_t)3072 * 1024;        // 1024 x 1024
  bf16* vt = woutT + (size_t)1024 * 1024;           // (B*H) x 64 x 2048
  bf16* attn = vt + (size_t)B_ * H_ * D_ * S_;      // 4096 x 1024

  prep<<<dim3(8192), 256, 0, stream>>>(xb, wqkvT, woutT, x, wqkv, wout);
  gemm_qkv<<<dim3(32, 24), 256, 0, stream>>>(qkv, vt, xb, wqkvT);
  attn_flash<<<dim3(B_ * H_, S_ / 64), 256, 0, stream>>>(attn, qkv, vt);
  gemm_bt64<float><<<dim3(64, 8), 256, 0, stream>>>(out, attn, woutT, 4096, E_, E_);
}